// Round 5
// baseline (744.006 us; speedup 1.0000x reference)
//
#include <hip/hip_runtime.h>
#include <hip/hip_bf16.h>

// CensorNet T=512,B=256,I=128,H=256 GRU scan + BCE decode.
// R5: fused producer/consumer chunking: blocks 0..127 = recurrence for chunk
// k (128 WGs x 2 batch rows, 1 gate elem/lane), blocks 128+ = gi GEMM for
// chunk k+1 into the other gi buffer (no intra-launch dependency; kernel
// boundary orders producer->consumer). Conflict-free xbuf (33-word stride),
// exec-masked hbf loads (only 2 real B rows), shfl-packed h writes.

typedef __bf16 bf16x8_t __attribute__((ext_vector_type(8)));
typedef float floatx4_t __attribute__((ext_vector_type(4)));
typedef int intx4_t __attribute__((ext_vector_type(4)));
typedef unsigned int u32;
typedef u32 u32x2_t __attribute__((ext_vector_type(2)));

#define SW 2032.0f
#define SH 127.0f
#define INV_S (1.0f / (127.0f * 2032.0f))
#define NL2E (-1.44269504088896f) /* -log2(e) */
#define CRZ (NL2E * INV_S)
#define CN (2.0f * NL2E * INV_S)

static __device__ inline u32 pack2bf(float a, float b) {
  __bf16 x = (__bf16)a, y = (__bf16)b;
  unsigned short ux = *(unsigned short*)&x, uy = *(unsigned short*)&y;
  return (u32)ux | ((u32)uy << 16);
}

// ---------------- prep: quantize W_hh/W_dec to i8, zero h_ws/out ----------
__global__ void prep_kernel(const float* __restrict__ Whh,
                            const float* __restrict__ Wdec,
                            char* __restrict__ Wq, char* __restrict__ wdq,
                            float* __restrict__ h_ws, float* __restrict__ out) {
  int idx = blockIdx.x * 256 + threadIdx.x;  // 65536 total
  for (int i = idx; i < 768 * 256; i += 65536) {
    int v = (int)rintf(Whh[i] * SW);
    v = v > 127 ? 127 : (v < -127 ? -127 : v);
    Wq[i] = (char)v;
  }
  if (idx < 256) {
    int v = (int)rintf(Wdec[idx] * SW);
    v = v > 127 ? 127 : (v < -127 ? -127 : v);
    wdq[idx] = (char)v;
  }
  if (idx < 65536) h_ws[idx] = 0.f;
  if (idx == 0) out[0] = 0.f;
}

// ---------------- fused: rec (blocks 0..127) + gi gemm (blocks 128+) ------
// gi unit layout (u32 = 2 bf16, cols n,n+1), per (t_local, gblk4):
//   U = ((t*64 + gblk4)*24 + gate*8 + w2)*64 + r4*16 + s*8 + ((n&15)>>1)
// where b = t*256 + gblk4*4 + r4, n = gate*256 + w2*32 + s*16 + (n&15).
// Pre-scaled: r,z: NL2E*(gi+bih+bhh); n: 2*NL2E*(gi+bih).
__global__ __launch_bounds__(512) void fused_kernel(
    const char* __restrict__ Wq,   // [768][256] i8
    const char* __restrict__ wdq,  // [256] i8
    const float* __restrict__ x,   // [512*256][128]
    const float* __restrict__ Wih, // [768][128]
    const float* __restrict__ bih, const float* __restrict__ bhh,
    const float* __restrict__ gt, const float* __restrict__ bdec,
    float* __restrict__ h_ws, float* __restrict__ out,
    const u32* __restrict__ gir,   // gi for this rec chunk
    u32* __restrict__ giw,         // gi for next chunk (gemm role)
    int t0, int tc, int tg0, int tgc) {
  __shared__ __align__(16) char smem[104448];
  const int tid = threadIdx.x;
  const int w = tid >> 6, lane = tid & 63;
  const int q = lane >> 4, nh = lane & 15;

  if (blockIdx.x < 128) {
    // ================= rec role =================
    if (tc == 0) return;
    const int row = lane >> 5, col = lane & 31;  // gate-phase mapping
    const int g = blockIdx.x;                    // batch pair 0..127
    const int s = col >> 4, c15 = col & 15;
    const int colG = w * 32 + col;
    char* hbp = smem;                       // 2 x [16][256] i8
    int* xb = (int*)(smem + 8192);          // 8 waves x 200 words
    float* logitb = (float*)(smem + 14592); // up to 1024 floats

    // W_hh fragments (i8, A-operand): wave w owns cols w*32..+31 per gate
    intx4_t wf[6][4];
#pragma unroll
    for (int c = 0; c < 3; ++c)
#pragma unroll
      for (int ss = 0; ss < 2; ++ss) {
        const int n = c * 256 + w * 32 + ss * 16 + nh;
#pragma unroll
        for (int kb = 0; kb < 4; ++kb)
          wf[c * 2 + ss][kb] =
              *(const intx4_t*)(Wq + (size_t)n * 256 + kb * 64 + q * 16);
      }
    intx4_t wdf[4];
#pragma unroll
    for (int kb = 0; kb < 4; ++kb) {
      intx4_t z = {0, 0, 0, 0};
      intx4_t v = *(const intx4_t*)(wdq + kb * 64 + q * 16);
      wdf[kb] = (nh == 0) ? v : z;
    }
    const float bn2 = 2.0f * NL2E * bhh[512 + colG];
    const float bdec0 = bdec[0];

    // zero hb rows 2..15 (both buffers)
    for (int idx = tid; idx < 1792; idx += 512) {
      const int b = idx / 896, off = idx - b * 896;
      *(u32*)(hbp + b * 4096 + 512 + off * 4) = 0;
    }
    // stage initial h rows 0..1 (quantized) into buffer 0
    if (tid < 128) {
      const int r = tid >> 6, c0 = (tid & 63) * 4;
      u32 p = 0;
#pragma unroll
      for (int j = 0; j < 4; ++j) {
        int a = (int)rintf(h_ws[(size_t)(g * 2 + r) * 256 + c0 + j] * SH);
        a = a > 127 ? 127 : (a < -127 ? -127 : a);
        p |= ((u32)(a & 255)) << (8 * j);
      }
      *(u32*)(hbp + r * 256 + c0) = p;
    }
    float ho = h_ws[(size_t)(g * 2 + row) * 256 + colG];
    __syncthreads();

    const size_t u0 = ((size_t)(g >> 1) * 24 + w) * 64 +
                      (size_t)(((g & 1) * 2 + row) * 16 + s * 8 + (c15 >> 1));
    u32 gcur[3], gnxt[3];
#pragma unroll
    for (int c = 0; c < 3; ++c) gcur[c] = gir[u0 + c * 512];
    float loss = 0.f;
    const u32 par = (u32)(col & 1);

#pragma unroll 1
    for (int t = 0; t < tc; ++t) {
      const int pb = t & 1;
      {
        const int tp = (t + 1 < tc) ? t + 1 : t;
        const size_t un = (size_t)tp * 98304 + u0;
#pragma unroll
        for (int c = 0; c < 3; ++c) gnxt[c] = gir[un + c * 512];
      }

      intx4_t hbf[4];
#pragma unroll
      for (int kb = 0; kb < 4; ++kb) {
        intx4_t z = {0, 0, 0, 0};
        hbf[kb] = z;
      }
      if (nh < 2) {
#pragma unroll
        for (int kb = 0; kb < 4; ++kb)
          hbf[kb] =
              *(const intx4_t*)(hbp + pb * 4096 + nh * 256 + kb * 64 + q * 16);
      }

      intx4_t acc[6], facc;
#pragma unroll
      for (int cs = 0; cs < 6; ++cs)
#pragma unroll
        for (int j = 0; j < 4; ++j) acc[cs][j] = 0;
#pragma unroll
      for (int j = 0; j < 4; ++j) facc[j] = 0;

#pragma unroll
      for (int kb = 0; kb < 4; ++kb) {
#pragma unroll
        for (int cs = 0; cs < 6; ++cs)
          acc[cs] = __builtin_amdgcn_mfma_i32_16x16x64_i8(wf[cs][kb], hbf[kb],
                                                          acc[cs], 0, 0, 0);
        if (w == 0)
          facc = __builtin_amdgcn_mfma_i32_16x16x64_i8(wdf[kb], hbf[kb], facc,
                                                       0, 0, 0);
      }

      // conflict-free wave-private transpose (33-word cs stride)
      if (nh < 2) {
#pragma unroll
        for (int cs = 0; cs < 6; ++cs)
          *(intx4_t*)&xb[w * 200 + cs * 33 + nh * 16 + q * 4] = acc[cs];
      }
      const int aR = xb[w * 200 + s * 33 + row * 16 + c15];
      const int aZ = xb[w * 200 + (2 + s) * 33 + row * 16 + c15];
      const int aN = xb[w * 200 + (4 + s) * 33 + row * 16 + c15];

      const float gr =
          __uint_as_float(par ? (gcur[0] & 0xffff0000u) : (gcur[0] << 16));
      const float gz =
          __uint_as_float(par ? (gcur[1] & 0xffff0000u) : (gcur[1] << 16));
      const float gn =
          __uint_as_float(par ? (gcur[2] & 0xffff0000u) : (gcur[2] << 16));

      float rr = __builtin_amdgcn_rcpf(
          1.f + __builtin_amdgcn_exp2f(__builtin_fmaf((float)aR, CRZ, gr)));
      float zz = __builtin_amdgcn_rcpf(
          1.f + __builtin_amdgcn_exp2f(__builtin_fmaf((float)aZ, CRZ, gz)));
      float hn2 = __builtin_fmaf((float)aN, CN, bn2);
      float tv = 2.f * __builtin_amdgcn_rcpf(
                           1.f + __builtin_amdgcn_exp2f(
                                     __builtin_fmaf(rr, hn2, gn))) -
                 1.f;
      float hnew = tv + zz * (ho - tv);
      ho = hnew;
      int hq = (int)rintf(hnew * SH);
      hq = hq > 127 ? 127 : (hq < -127 ? -127 : hq);
      u32 b0 = (u32)(hq & 255);
      u32 b1 = (u32)__shfl_down((int)b0, 1);
      u32 b2 = (u32)__shfl_down((int)b0, 2);
      u32 b3 = (u32)__shfl_down((int)b0, 3);
      if ((col & 3) == 0)
        *(u32*)(hbp + (1 - pb) * 4096 + row * 256 + colG) =
            b0 | (b1 << 8) | (b2 << 16) | (b3 << 24);

      if (w == 0 && q == 0 && nh < 2 && t >= 1)
        logitb[(t - 1) * 2 + nh] = (float)facc[0] * INV_S + bdec0;
      __syncthreads();
#pragma unroll
      for (int c = 0; c < 3; ++c) gcur[c] = gnxt[c];
    }

    // tail decode of final h
    if (w == 0) {
      intx4_t hbf2[4], fac2;
#pragma unroll
      for (int kb = 0; kb < 4; ++kb) {
        intx4_t z = {0, 0, 0, 0};
        hbf2[kb] = z;
      }
      if (nh < 2) {
#pragma unroll
        for (int kb = 0; kb < 4; ++kb)
          hbf2[kb] = *(const intx4_t*)(hbp + (tc & 1) * 4096 + nh * 256 +
                                       kb * 64 + q * 16);
      }
#pragma unroll
      for (int j = 0; j < 4; ++j) fac2[j] = 0;
#pragma unroll
      for (int kb = 0; kb < 4; ++kb)
        fac2 = __builtin_amdgcn_mfma_i32_16x16x64_i8(wdf[kb], hbf2[kb], fac2,
                                                     0, 0, 0);
      if (q == 0 && nh < 2)
        logitb[(tc - 1) * 2 + nh] = (float)fac2[0] * INV_S + bdec0;
    }
    __syncthreads();

    // bulk BCE sweep
    for (int i = tid; i < tc * 2; i += 512) {
      float l = logitb[i];
      float gtv = gt[(size_t)(t0 + (i >> 1) + 1) * 256 + g * 2 + (i & 1)];
      float t1 = log1pf(__expf(-fabsf(l)));
      loss += gtv * (fmaxf(-l, 0.f) + t1) + (1.f - gtv) * (fmaxf(l, 0.f) + t1);
    }
    loss += __shfl_xor(loss, 1);
    loss += __shfl_xor(loss, 2);
    loss += __shfl_xor(loss, 4);
    loss += __shfl_xor(loss, 8);
    loss += __shfl_xor(loss, 16);
    loss += __shfl_xor(loss, 32);
    if (lane == 0) atomicAdd(out, loss);

    h_ws[(size_t)(g * 2 + row) * 256 + colG] = ho;
  } else {
    // ================= gemm role: gi for next chunk =================
    const int gb = blockIdx.x - 128;
    const int bn = gb % 6, bb = gb / 6;  // n-tile 0..5, step bb < tgc
    const int n0 = bn * 128;
    __bf16(*As)[136] = (__bf16(*)[136])smem;            // Wih tile 128 rows
    __bf16(*Bs)[136] = (__bf16(*)[136])(smem + 34816);  // x tile 256 rows

    {
      const int r = tid >> 2, cc = (tid & 3) * 32;
      const floatx4_t* src =
          (const floatx4_t*)(Wih + (size_t)(n0 + r) * 128 + cc);
#pragma unroll
      for (int v = 0; v < 4; ++v) {
        floatx4_t a = src[v * 2], b = src[v * 2 + 1];
        bf16x8_t t;
#pragma unroll
        for (int j = 0; j < 4; ++j) {
          t[j] = (__bf16)a[j];
          t[4 + j] = (__bf16)b[j];
        }
        *(bf16x8_t*)&As[r][cc + v * 8] = t;
      }
      const int r2 = tid >> 1, c2 = (tid & 1) * 64;
      const floatx4_t* src2 = (const floatx4_t*)(
          x + ((size_t)(tg0 + bb) * 256 + r2) * 128 + c2);
#pragma unroll
      for (int v = 0; v < 8; ++v) {
        floatx4_t a = src2[v * 2], b = src2[v * 2 + 1];
        bf16x8_t t;
#pragma unroll
        for (int j = 0; j < 4; ++j) {
          t[j] = (__bf16)a[j];
          t[4 + j] = (__bf16)b[j];
        }
        *(bf16x8_t*)&Bs[r2][c2 + v * 8] = t;
      }
    }
    __syncthreads();

    const int wm = w >> 2, wb = w & 3;
    floatx4_t acc[4][4];
#pragma unroll
    for (int a = 0; a < 4; ++a)
#pragma unroll
      for (int b = 0; b < 4; ++b)
#pragma unroll
        for (int j = 0; j < 4; ++j) acc[a][b][j] = 0.f;

#pragma unroll
    for (int kk = 0; kk < 4; ++kk) {
      bf16x8_t af[4], bf[4];
#pragma unroll
      for (int mt = 0; mt < 4; ++mt)
        af[mt] = *(const bf16x8_t*)&As[wm * 64 + mt * 16 + nh][kk * 32 + q * 8];
#pragma unroll
      for (int nt = 0; nt < 4; ++nt)
        bf[nt] = *(const bf16x8_t*)&Bs[wb * 64 + nt * 16 + nh][kk * 32 + q * 8];
#pragma unroll
      for (int mt = 0; mt < 4; ++mt)
#pragma unroll
        for (int nt = 0; nt < 4; ++nt)
          acc[mt][nt] = __builtin_amdgcn_mfma_f32_16x16x32_bf16(
              af[mt], bf[nt], acc[mt][nt], 0, 0, 0);
    }

#pragma unroll
    for (int mt = 0; mt < 4; ++mt) {
      const int nn = n0 + wm * 64 + mt * 16 + q * 4;
      const int gate = nn >> 8;
      const float sc = (gate < 2) ? NL2E : (2.0f * NL2E);
      floatx4_t bias = *(const floatx4_t*)(bih + nn);
      if (gate < 2) {
        floatx4_t b2 = *(const floatx4_t*)(bhh + nn);
#pragma unroll
        for (int j = 0; j < 4; ++j) bias[j] += b2[j];
      }
      const int w2 = (nn & 255) >> 5;
      const int Lb = (mt & 1) * 8 + q * 2;
#pragma unroll
      for (int nt = 0; nt < 4; ++nt) {
        const int brow = wb * 64 + nt * 16 + nh;  // 0..255 within step
        const int gg = brow >> 2, rr = brow & 3;
        size_t U =
            (((size_t)bb * 64 + gg) * 24 + gate * 8 + w2) * 64 + rr * 16 + Lb;
        u32x2_t pv;
        pv.x = pack2bf((acc[mt][nt][0] + bias[0]) * sc,
                       (acc[mt][nt][1] + bias[1]) * sc);
        pv.y = pack2bf((acc[mt][nt][2] + bias[2]) * sc,
                       (acc[mt][nt][3] + bias[3]) * sc);
        *(u32x2_t*)(giw + U) = pv;
      }
    }
  }
}

// ---------------- host ----------------
extern "C" void kernel_launch(void* const* d_in, const int* in_sizes, int n_in,
                              void* d_out, int out_size, void* d_ws,
                              size_t ws_size, hipStream_t stream) {
  const float* x = (const float*)d_in[0];
  const float* gt = (const float*)d_in[1];
  const float* Wih = (const float*)d_in[2];
  const float* Whh = (const float*)d_in[3];
  const float* bih = (const float*)d_in[4];
  const float* bhh = (const float*)d_in[5];
  const float* Wdec = (const float*)d_in[6];
  const float* bdec = (const float*)d_in[7];
  float* out = (float*)d_out;

  char* ws = (char*)d_ws;
  char* Wq = ws;                        // 196608 B
  char* wdq = ws + 196608;              // 512 B
  float* h_ws = (float*)(ws + 197120);  // 262144 B
  u32* gi0 = (u32*)(ws + 524288);
  const size_t per_step = (size_t)256 * 768 * 2;  // 393216 B
  size_t avail = ws_size > 524288 ? ws_size - 524288 : per_step;
  size_t cap = avail / per_step;

  prep_kernel<<<256, 256, 0, stream>>>(Whh, Wdec, Wq, wdq, h_ws, out);

  if (cap >= 8) {
    // pipelined: double-buffered gi, gemm for chunk k+1 fused with rec k
    int Tc = (int)(cap / 2 < 64 ? cap / 2 : 64);
    u32* gi1 = (u32*)((char*)gi0 + (size_t)Tc * per_step);
    u32* bufs[2] = {gi0, gi1};
    const int nch = (511 + Tc - 1) / Tc;
    auto clen = [&](int k) {
      int s = k * Tc, L = 511 - s;
      return L > Tc ? Tc : L;
    };
    int tc0 = clen(0);
    fused_kernel<<<128 + 6 * tc0, 512, 0, stream>>>(
        Wq, wdq, x, Wih, bih, bhh, gt, bdec, h_ws, out, bufs[0], bufs[0], 0, 0,
        0, tc0);
    for (int k = 0; k < nch; ++k) {
      const int tck = clen(k);
      const int tgn = (k + 1 < nch) ? clen(k + 1) : 0;
      fused_kernel<<<128 + 6 * tgn, 512, 0, stream>>>(
          Wq, wdq, x, Wih, bih, bhh, gt, bdec, h_ws, out, bufs[k & 1],
          bufs[(k + 1) & 1], k * Tc, tck, (k + 1) * Tc, tgn);
    }
  } else {
    // serial fallback: single gi buffer, gemm then rec per chunk
    int Tc = (int)(cap < 1 ? 1 : (cap > 511 ? 511 : cap));
    for (int t0 = 0; t0 < 511; t0 += Tc) {
      const int tck = (511 - t0 < Tc) ? (511 - t0) : Tc;
      fused_kernel<<<128 + 6 * tck, 512, 0, stream>>>(
          Wq, wdq, x, Wih, bih, bhh, gt, bdec, h_ws, out, gi0, gi0, 0, 0, t0,
          tck);
      fused_kernel<<<128, 512, 0, stream>>>(Wq, wdq, x, Wih, bih, bhh, gt,
                                            bdec, h_ws, out, gi0, gi0, t0, tck,
                                            0, 0);
    }
  }
}